// Round 6
// baseline (1082.929 us; speedup 1.0000x reference)
//
#include <hip/hip_runtime.h>

// ---------------------------------------------------------------------------
// HopfieldPooling on MI355X (gfx950)
//   x -> xh/xl planar bf16 (preconversion; ws-size guarded)
//   k = x@Wk^T: BARRIER-FREE split-bf16 MFMA gemm (A and B register-direct,
//       no LDS, no syncthreads -> compiler/vmcnt pipelined). Output k packed
//       (hi|lo<<16) in HEAD-MAJOR layout [b][h][n][64] for contiguous attn reads.
//   q0 = query@Wq^T (fp32)
//   3x Hopfield steps: wave-independent flash tiles, softmax_1 fixed shift 0,
//       in-register P (row-permuted QK), register prefetch, contiguous k streams
//   out = (q@Wv^T)@Wproj^T + b  (fp32 vector)
// ---------------------------------------------------------------------------

typedef float  float4v  __attribute__((ext_vector_type(4)));
typedef short  short4v  __attribute__((ext_vector_type(4)));
typedef short  short8v  __attribute__((ext_vector_type(8)));
typedef unsigned int uint4v __attribute__((ext_vector_type(4)));
typedef short8v bf16x8;   // 8 bf16 = 4 VGPRs, MFMA A/B frag

#define NC 4   // n-chunks per (b,h) in attention step

__device__ __forceinline__ unsigned short f2bf_hi(float f){
  unsigned int u = __float_as_uint(f);
  u += 0x7fffu + ((u >> 16) & 1u);            // round-to-nearest-even
  return (unsigned short)(u >> 16);
}
__device__ __forceinline__ float bf2f(unsigned short h){
  return __uint_as_float(((unsigned int)h) << 16);
}
__device__ __forceinline__ unsigned int packbf(float v){
  unsigned short hh = f2bf_hi(v);
  return (unsigned)hh | ((unsigned)f2bf_hi(v - bf2f(hh)) << 16);
}

// ---------------------------------------------------------------------------
// fp32 -> planar hi/lo bf16 (Wk 768x768 and x 16x4096x768)
// ---------------------------------------------------------------------------
__global__ __launch_bounds__(256)
void cvt_planar_kernel(const float* __restrict__ src, unsigned short* __restrict__ dh,
                       unsigned short* __restrict__ dl){
  size_t idx = (size_t)blockIdx.x*256 + threadIdx.x;
  float4v v = ((const float4v*)src)[idx];
  short4v h4, l4;
  #pragma unroll
  for(int e=0;e<4;e++){
    unsigned short hh = f2bf_hi(v[e]);
    h4[e] = (short)hh;
    l4[e] = (short)f2bf_hi(v[e] - bf2f(hh));
  }
  ((short4v*)dh)[idx] = h4;
  ((short4v*)dl)[idx] = l4;
}

// ---------------------------------------------------------------------------
// q0[l][c] = sum_j query[l][j]*Wq[c][j]   (16x768, fp32)
// ---------------------------------------------------------------------------
__global__ __launch_bounds__(256)
void q0_kernel(const float* __restrict__ query, const float* __restrict__ wq,
               float* __restrict__ q0){
  int idx = blockIdx.x*256 + threadIdx.x;     // 12288
  int l = idx / 768, c = idx - l*768;
  const float* qr = query + l*768;
  const float* wr = wq + (size_t)c*768;
  float s = 0.f;
  for(int j=0;j<768;j+=4){
    float4v a  = *(const float4v*)(qr+j);
    float4v w4 = *(const float4v*)(wr+j);
    s += a[0]*w4[0]+a[1]*w4[1]+a[2]*w4[2]+a[3]*w4[3];
  }
  q0[idx] = s;
}

// ---------------------------------------------------------------------------
// Barrier-free k-GEMM (preconverted x): M=65536, N=768, K=768.
// Block 128x128, 4 waves in 2x2, wave tile 64x64 (4x4 16x16x32 subtiles).
// A frags from xh/xl planes, B frags from wh/wl planes — all register-direct,
// no LDS, no __syncthreads. XCD swizzle. Output: packed k, head-major
// khead[((b*12+h)*4096 + n)*64 + d].
// ---------------------------------------------------------------------------
__global__ __launch_bounds__(256, 3)
void gemm_k_pre_kernel(const unsigned short* __restrict__ xh, const unsigned short* __restrict__ xl,
                       const unsigned short* __restrict__ wh, const unsigned short* __restrict__ wl,
                       unsigned int* __restrict__ khead){
  const int tid  = threadIdx.x;
  const int id   = blockIdx.x;          // 0..3071
  const int xcd  = id & 7, slot = id >> 3;
  const int bml  = slot / 6;            // 0..63
  const int bn   = slot - bml*6;        // 0..5
  const int bm   = xcd*64 + bml;        // 0..511
  const int wave = tid >> 6, lane = tid & 63, quad = lane >> 4, l16 = lane & 15;
  const int wr   = wave >> 1, wc = wave & 1;

  float4v acc[4][4];
  #pragma unroll
  for(int i=0;i<4;i++)
    #pragma unroll
    for(int j=0;j<4;j++) acc[i][j] = (float4v){0.f,0.f,0.f,0.f};

  const size_t aoff = (size_t)(bm*128 + wr*64 + l16)*768 + quad*8;
  const size_t boff = (size_t)(bn*128 + wc*64 + l16)*768 + quad*8;
  const unsigned short* pah = xh + aoff;
  const unsigned short* pal = xl + aoff;
  const unsigned short* pbh = wh + boff;
  const unsigned short* pbl = wl + boff;

  for(int k0=0;k0<768;k0+=32){
    bf16x8 ah[4], al[4], bh[4], bl[4];
    #pragma unroll
    for(int i=0;i<4;i++){
      ah[i] = *(const bf16x8*)(pah + (size_t)i*16*768 + k0);
      al[i] = *(const bf16x8*)(pal + (size_t)i*16*768 + k0);
      bh[i] = *(const bf16x8*)(pbh + (size_t)i*16*768 + k0);
      bl[i] = *(const bf16x8*)(pbl + (size_t)i*16*768 + k0);
    }
    #pragma unroll
    for(int i=0;i<4;i++)
      #pragma unroll
      for(int j=0;j<4;j++){
        acc[i][j] = __builtin_amdgcn_mfma_f32_16x16x32_bf16(ah[i], bh[j], acc[i][j],0,0,0);
        acc[i][j] = __builtin_amdgcn_mfma_f32_16x16x32_bf16(al[i], bh[j], acc[i][j],0,0,0);
        acc[i][j] = __builtin_amdgcn_mfma_f32_16x16x32_bf16(ah[i], bl[j], acc[i][j],0,0,0);
      }
  }
  // epilogue: head-major packed store
  const int b     = bm >> 5;                 // 32 blocks per batch
  const int h     = bn*2 + wc;
  const int nbase = (bm & 31)*128 + wr*64;
  unsigned int* kout = khead + (size_t)(b*12 + h)*4096*64;
  #pragma unroll
  for(int i=0;i<4;i++)
    #pragma unroll
    for(int j=0;j<4;j++)
      #pragma unroll
      for(int r=0;r<4;r++){
        const int n = nbase + i*16 + quad*4 + r;
        kout[(size_t)n*64 + j*16 + l16] = packbf(acc[i][j][r]);
      }
}

// ---------------------------------------------------------------------------
// Fallback barrier-free gemm: A loaded fp32 from x, converted in-register.
// ---------------------------------------------------------------------------
__global__ __launch_bounds__(256, 3)
void gemm_k_fly_kernel(const float* __restrict__ x,
                       const unsigned short* __restrict__ wh, const unsigned short* __restrict__ wl,
                       unsigned int* __restrict__ khead){
  const int tid  = threadIdx.x;
  const int id   = blockIdx.x;
  const int xcd  = id & 7, slot = id >> 3;
  const int bml  = slot / 6;
  const int bn   = slot - bml*6;
  const int bm   = xcd*64 + bml;
  const int wave = tid >> 6, lane = tid & 63, quad = lane >> 4, l16 = lane & 15;
  const int wr   = wave >> 1, wc = wave & 1;

  float4v acc[4][4];
  #pragma unroll
  for(int i=0;i<4;i++)
    #pragma unroll
    for(int j=0;j<4;j++) acc[i][j] = (float4v){0.f,0.f,0.f,0.f};

  const float* pax = x + (size_t)(bm*128 + wr*64 + l16)*768 + quad*8;
  const size_t boff = (size_t)(bn*128 + wc*64 + l16)*768 + quad*8;
  const unsigned short* pbh = wh + boff;
  const unsigned short* pbl = wl + boff;

  for(int k0=0;k0<768;k0+=32){
    bf16x8 ah[4], al[4], bh[4], bl[4];
    #pragma unroll
    for(int i=0;i<4;i++){
      const float* sp = pax + (size_t)i*16*768 + k0;
      float4v va = *(const float4v*)sp;
      float4v vb = *(const float4v*)(sp + 4);
      #pragma unroll
      for(int e=0;e<4;e++){
        unsigned short hh = f2bf_hi(va[e]);
        ah[i][e] = (short)hh; al[i][e] = (short)f2bf_hi(va[e] - bf2f(hh));
        unsigned short hh2 = f2bf_hi(vb[e]);
        ah[i][e+4] = (short)hh2; al[i][e+4] = (short)f2bf_hi(vb[e] - bf2f(hh2));
      }
      bh[i] = *(const bf16x8*)(pbh + (size_t)i*16*768 + k0);
      bl[i] = *(const bf16x8*)(pbl + (size_t)i*16*768 + k0);
    }
    #pragma unroll
    for(int i=0;i<4;i++)
      #pragma unroll
      for(int j=0;j<4;j++){
        acc[i][j] = __builtin_amdgcn_mfma_f32_16x16x32_bf16(ah[i], bh[j], acc[i][j],0,0,0);
        acc[i][j] = __builtin_amdgcn_mfma_f32_16x16x32_bf16(al[i], bh[j], acc[i][j],0,0,0);
        acc[i][j] = __builtin_amdgcn_mfma_f32_16x16x32_bf16(ah[i], bl[j], acc[i][j],0,0,0);
      }
  }
  const int b     = bm >> 5;
  const int h     = bn*2 + wc;
  const int nbase = (bm & 31)*128 + wr*64;
  unsigned int* kout = khead + (size_t)(b*12 + h)*4096*64;
  #pragma unroll
  for(int i=0;i<4;i++)
    #pragma unroll
    for(int j=0;j<4;j++)
      #pragma unroll
      for(int r=0;r<4;r++){
        const int n = nbase + i*16 + quad*4 + r;
        kout[(size_t)n*64 + j*16 + l16] = packbf(acc[i][j][r]);
      }
}

// ---------------------------------------------------------------------------
// Attention step v6: head-major contiguous k. Wave-independent 32-row slices,
// in-register softmax (QK A-rows permuted so D-layout == PV A-layout),
// register prefetch of next 128x64 tile, 2 barriers/tile.
// ---------------------------------------------------------------------------
__global__ __launch_bounds__(256, 3)
void attn_step_kernel(const unsigned int* __restrict__ khead, const float* __restrict__ qsrc,
                      long qb_stride, float* __restrict__ qacc, float* __restrict__ lacc){
  __shared__ unsigned int knd[128*68];  // packed (hi|lo<<16), stride 68 words
  __shared__ float red[4][16];

  const int tid  = threadIdx.x;
  const int c    = blockIdx.x;          // 0..NC-1
  const int h    = blockIdx.y;          // 0..11
  const int b    = blockIdx.z;          // 0..15
  const int wave = tid >> 6, lane = tid & 63, quad = lane >> 4, l16 = lane & 15;

  // contiguous chunk: 1024 rows x 64 d
  const unsigned int* kb = khead + ((size_t)(b*12 + h)*4096 + (size_t)c*1024)*64;

  // q fragments (scale 1/8 folded), split hi/lo. lane l16 = l.
  const float* qp = qsrc + (size_t)b*qb_stride + (size_t)l16*768 + h*64;
  bf16x8 qh[2], ql[2];
  #pragma unroll
  for(int s = 0; s < 2; ++s){
    float4v v0 = *(const float4v*)(qp + s*32 + quad*8);
    float4v v1 = *(const float4v*)(qp + s*32 + quad*8 + 4);
    #pragma unroll
    for(int e = 0; e < 8; ++e){
      float v = (e < 4 ? v0[e] : v1[e-4]) * 0.125f;
      unsigned short hh = f2bf_hi(v);
      qh[s][e] = (short)hh;
      ql[s][e] = (short)f2bf_hi(v - bf2f(hh));
    }
  }

  float4v acc[4];
  #pragma unroll
  for(int j=0;j<4;j++) acc[j] = (float4v){0.f,0.f,0.f,0.f};
  float lsum = 0.f;

  // staging map: chunk g (4 KB) = rows [g*16, g*16+16); thread covers
  // row g*16 + (tid>>4), u32 col (tid&15)*4. Fully coalesced loads.
  const int srow = tid >> 4, scol = (tid & 15)*4;
  const int T = (1024)/128;   // 8 tiles per chunk
  uint4v pf[8];
  {
    const unsigned int* src = kb + tid*4;
    #pragma unroll
    for(int g=0; g<8; ++g) pf[g] = *(const uint4v*)(src + g*1024);
  }

  // QK A-row permutation: sigma(l16) = 8*(l16>>2) + (l16&3)
  const int rA = wave*32 + 8*(l16 >> 2) + (l16 & 3);

  for(int t = 0; t < T; ++t){
    // ---- write prefetched tile to LDS ----
    #pragma unroll
    for(int g=0; g<8; ++g)
      *(uint4v*)(knd + (g*16 + srow)*68 + scol) = pf[g];
    __syncthreads();                                   // staged
    if(t+1 < T){
      const unsigned int* src = kb + (size_t)(t+1)*8192 + tid*4;
      #pragma unroll
      for(int g=0; g<8; ++g) pf[g] = *(const uint4v*)(src + g*1024);
    }

    // ---- QK: s1 covers n-local 8q+r, s2 covers 8q+4+r (per lane) ----
    float4v s1 = (float4v){0.f,0.f,0.f,0.f};
    float4v s2 = (float4v){0.f,0.f,0.f,0.f};
    #pragma unroll
    for(int s = 0; s < 2; ++s){
      const unsigned int* a1p = knd + rA*68 + s*32 + quad*8;
      const unsigned int* a2p = a1p + 4*68;
      uint4v w0 = *(const uint4v*)a1p;
      uint4v w1 = *(const uint4v*)(a1p + 4);
      uint4v u0 = *(const uint4v*)a2p;
      uint4v u1 = *(const uint4v*)(a2p + 4);
      bf16x8 a1h, a1l, a2h, a2l;
      #pragma unroll
      for(int j = 0; j < 4; ++j){
        a1h[j]   = (short)(w0[j] & 0xffffu);  a1l[j]   = (short)(w0[j] >> 16);
        a1h[j+4] = (short)(w1[j] & 0xffffu);  a1l[j+4] = (short)(w1[j] >> 16);
        a2h[j]   = (short)(u0[j] & 0xffffu);  a2l[j]   = (short)(u0[j] >> 16);
        a2h[j+4] = (short)(u1[j] & 0xffffu);  a2l[j+4] = (short)(u1[j] >> 16);
      }
      s1 = __builtin_amdgcn_mfma_f32_16x16x32_bf16(a1h, qh[s], s1, 0,0,0);
      s1 = __builtin_amdgcn_mfma_f32_16x16x32_bf16(a1l, qh[s], s1, 0,0,0);
      s1 = __builtin_amdgcn_mfma_f32_16x16x32_bf16(a1h, ql[s], s1, 0,0,0);
      s2 = __builtin_amdgcn_mfma_f32_16x16x32_bf16(a2h, qh[s], s2, 0,0,0);
      s2 = __builtin_amdgcn_mfma_f32_16x16x32_bf16(a2l, qh[s], s2, 0,0,0);
      s2 = __builtin_amdgcn_mfma_f32_16x16x32_bf16(a2h, ql[s], s2, 0,0,0);
    }

    // ---- exp + split P (in registers; D-layout == PV A-layout) ----
    bf16x8 pa_h, pa_l;
    #pragma unroll
    for(int e = 0; e < 4; ++e){
      float v = __expf(s1[e]);
      lsum += v;
      unsigned short hh = f2bf_hi(v);
      pa_h[e] = (short)hh;
      pa_l[e] = (short)f2bf_hi(v - bf2f(hh));
      float v2 = __expf(s2[e]);
      lsum += v2;
      unsigned short hh2 = f2bf_hi(v2);
      pa_h[e+4] = (short)hh2;
      pa_l[e+4] = (short)f2bf_hi(v2 - bf2f(hh2));
    }

    // ---- PV: acc[l][d] += P[l][n] k[n][d] over wave's 32 n (K=32) ----
    const unsigned int* bbase = knd + (size_t)(wave*32 + quad*8)*68 + l16;
    #pragma unroll
    for(int j = 0; j < 4; ++j){
      const unsigned int* bp = bbase + j*16;
      bf16x8 kbh, kbl;
      #pragma unroll
      for(int e = 0; e < 8; ++e){
        unsigned int w = bp[e*68];
        kbh[e] = (short)(w & 0xffffu);
        kbl[e] = (short)(w >> 16);
      }
      acc[j] = __builtin_amdgcn_mfma_f32_16x16x32_bf16(pa_h, kbh, acc[j], 0,0,0);
      acc[j] = __builtin_amdgcn_mfma_f32_16x16x32_bf16(pa_l, kbh, acc[j], 0,0,0);
      acc[j] = __builtin_amdgcn_mfma_f32_16x16x32_bf16(pa_h, kbl, acc[j], 0,0,0);
    }
    __syncthreads();                                   // compute done
  }

  // ---- epilogue: reduce lsum per l, atomic partials ----
  lsum += __shfl_xor(lsum, 16);
  lsum += __shfl_xor(lsum, 32);
  if(quad == 0) red[wave][l16] = lsum;
  __syncthreads();
  if(tid < 16){
    float tot = red[0][tid] + red[1][tid] + red[2][tid] + red[3][tid];
    atomicAdd(&lacc[(b*12 + h)*16 + tid], tot);
  }
  // acc mapping: l = quad*4+r, d = j*16+l16
  #pragma unroll
  for(int j = 0; j < 4; ++j)
    #pragma unroll
    for(int r = 0; r < 4; ++r)
      atomicAdd(&qacc[(size_t)(b*16 + quad*4 + r)*768 + h*64 + j*16 + l16], acc[j][r]);
}

// ---------------------------------------------------------------------------
// Normalize: qcur = qacc / (1 + lacc); then zero qacc/lacc for the next step.
// ---------------------------------------------------------------------------
__global__ __launch_bounds__(256)
void attn_norm_kernel(float* __restrict__ qacc, float* __restrict__ lacc,
                      float* __restrict__ qcur){
  __shared__ float lt[16];
  const int bh = blockIdx.x, b = bh/12, h = bh - (bh/12)*12, tid = threadIdx.x;
  if(tid < 16) lt[tid] = 1.f + lacc[bh*16 + tid];
  __syncthreads();
  if(tid < 16) lacc[bh*16 + tid] = 0.f;
  for(int idx = tid; idx < 1024; idx += 256){
    int l = idx >> 6, d = idx & 63;
    size_t a = (size_t)(b*16 + l)*768 + h*64 + d;
    qcur[a] = qacc[a] / lt[l];
    qacc[a] = 0.f;
  }
}

// ---------------------------------------------------------------------------
// out[r][c] = sum_j inp[r][j]*W[c][j] (+bias). 4 rows x 256 cols per block.
// ---------------------------------------------------------------------------
__global__ __launch_bounds__(256)
void proj_kernel(const float* __restrict__ inp, const float* __restrict__ w,
                 const float* __restrict__ bias, float* __restrict__ out){
  __shared__ float rows[4*768];
  const int r0 = blockIdx.x*4;
  const int c  = blockIdx.y*256 + threadIdx.x;
  for(int j = threadIdx.x; j < 4*768; j += 256) rows[j] = inp[(size_t)r0*768 + j];
  __syncthreads();
  const float* wr = w + (size_t)c*768;
  float a0=0.f, a1=0.f, a2=0.f, a3=0.f;
  for(int j=0;j<768;j+=4){
    float4v w4 = *(const float4v*)(wr+j);
    float4v r0v = *(const float4v*)(rows+j);
    float4v r1v = *(const float4v*)(rows+768+j);
    float4v r2v = *(const float4v*)(rows+1536+j);
    float4v r3v = *(const float4v*)(rows+2304+j);
    #pragma unroll
    for(int e=0;e<4;e++){
      a0 += r0v[e]*w4[e]; a1 += r1v[e]*w4[e];
      a2 += r2v[e]*w4[e]; a3 += r3v[e]*w4[e];
    }
  }
  const float bb = bias ? bias[c] : 0.f;
  out[(size_t)(r0+0)*768 + c] = a0 + bb;
  out[(size_t)(r0+1)*768 + c] = a1 + bb;
  out[(size_t)(r0+2)*768 + c] = a2 + bb;
  out[(size_t)(r0+3)*768 + c] = a3 + bb;
}

// ---------------------------------------------------------------------------
extern "C" void kernel_launch(void* const* d_in, const int* in_sizes, int n_in,
                              void* d_out, int out_size, void* d_ws, size_t ws_size,
                              hipStream_t stream){
  const float* x     = (const float*)d_in[0];   // [16,4096,768]
  const float* query = (const float*)d_in[1];   // [1,16,768]
  const float* Wq    = (const float*)d_in[2];   // [768,768]
  const float* Wk    = (const float*)d_in[3];
  const float* Wv    = (const float*)d_in[4];
  const float* Wproj = (const float*)d_in[5];
  const float* bproj = (const float*)d_in[6];   // [768]
  float* out = (float*)d_out;                   // [16,16,768] fp32

  const size_t XB   = 100663296;   // xh / xl plane bytes
  const size_t KB_  = 201326592;   // packed k bytes
  const size_t PRE_NEED = 2*XB + KB_ + 786432 + 49152 + 2359296;  // ~387 MB (proven fits in r3)

  char* ws = (char*)d_ws;
  dim3 sg(NC, 12, 16);

  if(ws_size >= PRE_NEED){
    unsigned short* xh    = (unsigned short*)(ws);
    unsigned short* xl    = (unsigned short*)(ws + XB);
    unsigned int*   khead = (unsigned int*)  (ws + 2*XB);
    float*          qcur  = (float*)(ws + 2*XB + KB_);
    float*          q0    = (float*)(ws + 2*XB + KB_ + 786432);
    char*           R     = ws + 2*XB + KB_ + 786432 + 49152;
    unsigned short* wkh   = (unsigned short*)(R);
    unsigned short* wkl   = (unsigned short*)(R + 1179648);
    float*          qacc  = (float*)(R);          // alias after gemm
    float*          lacc  = (float*)(R + 786432);
    float*          out1  = (float*)(R);          // alias in proj phase

    cvt_planar_kernel<<<576, 256, 0, stream>>>(Wk, wkh, wkl);
    cvt_planar_kernel<<<49152, 256, 0, stream>>>(x, xh, xl);
    q0_kernel<<<48, 256, 0, stream>>>(query, Wq, q0);
    gemm_k_pre_kernel<<<3072, 256, 0, stream>>>(xh, xl, wkh, wkl, khead);

    hipMemsetAsync(qacc, 0, 786432 + 12288, stream);
    attn_step_kernel<<<sg, 256, 0, stream>>>(khead, q0,   0,       qacc, lacc);
    attn_norm_kernel<<<192, 256, 0, stream>>>(qacc, lacc, qcur);
    attn_step_kernel<<<sg, 256, 0, stream>>>(khead, qcur, 16*768,  qacc, lacc);
    attn_norm_kernel<<<192, 256, 0, stream>>>(qacc, lacc, qcur);
    attn_step_kernel<<<sg, 256, 0, stream>>>(khead, qcur, 16*768,  qacc, lacc);
    attn_norm_kernel<<<192, 256, 0, stream>>>(qacc, lacc, qcur);

    proj_kernel<<<dim3(64, 3), 256, 0, stream>>>(qcur, Wv, nullptr, out1);
    proj_kernel<<<dim3(64, 3), 256, 0, stream>>>(out1, Wproj, bproj, out);
  } else {
    unsigned int*   khead = (unsigned int*)(ws);           // 201326592 B
    float*          qcur  = (float*)(ws + 201326592);      // 786432 B
    float*          q0    = (float*)(ws + 202113024);      // 49152 B
    char*           R     = ws + 202162176;                // 2359296 B region
    unsigned short* wkh   = (unsigned short*)(R);
    unsigned short* wkl   = (unsigned short*)(R + 1179648);
    float*          qacc  = (float*)(R);
    float*          lacc  = (float*)(R + 786432);
    float*          out1  = (float*)(R);

    cvt_planar_kernel<<<576, 256, 0, stream>>>(Wk, wkh, wkl);
    q0_kernel<<<48, 256, 0, stream>>>(query, Wq, q0);
    gemm_k_fly_kernel<<<3072, 256, 0, stream>>>(x, wkh, wkl, khead);

    hipMemsetAsync(qacc, 0, 786432 + 12288, stream);
    attn_step_kernel<<<sg, 256, 0, stream>>>(khead, q0,   0,       qacc, lacc);
    attn_norm_kernel<<<192, 256, 0, stream>>>(qacc, lacc, qcur);
    attn_step_kernel<<<sg, 256, 0, stream>>>(khead, qcur, 16*768,  qacc, lacc);
    attn_norm_kernel<<<192, 256, 0, stream>>>(qacc, lacc, qcur);
    attn_step_kernel<<<sg, 256, 0, stream>>>(khead, qcur, 16*768,  qacc, lacc);
    attn_norm_kernel<<<192, 256, 0, stream>>>(qacc, lacc, qcur);

    proj_kernel<<<dim3(64, 3), 256, 0, stream>>>(qcur, Wv, nullptr, out1);
    proj_kernel<<<dim3(64, 3), 256, 0, stream>>>(out1, Wproj, bproj, out);
  }
}

// Round 7
// 709.936 us; speedup vs baseline: 1.5254x; 1.5254x over previous
//
#include <hip/hip_runtime.h>

// ---------------------------------------------------------------------------
// HopfieldPooling on MI355X (gfx950)
//   k = x@Wk^T  (split-bf16 MFMA, 3-term; A via LDS on-stage convert, B
//       register-direct from L2-resident W planes; XCD swizzle) -> packed
//       (hi|lo<<16) HEAD-MAJOR khead[b][h][n][64]
//   q0 = query@Wq^T (fp32)
//   attn3: ONE kernel, 192 blocks x 512 thr, all 3 Hopfield steps.
//       softmax_1 fixed shift 0. Wave-local 32-row LDS slices -> barrier-free
//       tile loop; block LDS reduction at iteration boundaries. 64 KB LDS,
//       stride-64 + XOR swizzle (<=2-way conflicts).
//   out = (q@Wv^T)@Wproj^T + b  (fp32 vector)
// ---------------------------------------------------------------------------

typedef float  float4v  __attribute__((ext_vector_type(4)));
typedef short  short4v  __attribute__((ext_vector_type(4)));
typedef short  short8v  __attribute__((ext_vector_type(8)));
typedef unsigned int uint4v __attribute__((ext_vector_type(4)));
typedef short8v bf16x8;   // 8 bf16 = 4 VGPRs, MFMA A/B frag

__device__ __forceinline__ unsigned short f2bf_hi(float f){
  unsigned int u = __float_as_uint(f);
  u += 0x7fffu + ((u >> 16) & 1u);            // round-to-nearest-even
  return (unsigned short)(u >> 16);
}
__device__ __forceinline__ float bf2f(unsigned short h){
  return __uint_as_float(((unsigned int)h) << 16);
}
__device__ __forceinline__ unsigned int packbf(float v){
  unsigned short hh = f2bf_hi(v);
  return (unsigned)hh | ((unsigned)f2bf_hi(v - bf2f(hh)) << 16);
}

// ---------------------------------------------------------------------------
// fp32 -> planar hi/lo bf16 (Wk 768x768)
// ---------------------------------------------------------------------------
__global__ __launch_bounds__(256)
void cvt_planar_kernel(const float* __restrict__ src, unsigned short* __restrict__ dh,
                       unsigned short* __restrict__ dl){
  size_t idx = (size_t)blockIdx.x*256 + threadIdx.x;
  float4v v = ((const float4v*)src)[idx];
  short4v h4, l4;
  #pragma unroll
  for(int e=0;e<4;e++){
    unsigned short hh = f2bf_hi(v[e]);
    h4[e] = (short)hh;
    l4[e] = (short)f2bf_hi(v[e] - bf2f(hh));
  }
  ((short4v*)dh)[idx] = h4;
  ((short4v*)dl)[idx] = l4;
}

// ---------------------------------------------------------------------------
// q0[l][c] = sum_j query[l][j]*Wq[c][j]   (16x768, fp32)
// ---------------------------------------------------------------------------
__global__ __launch_bounds__(256)
void q0_kernel(const float* __restrict__ query, const float* __restrict__ wq,
               float* __restrict__ q0){
  int idx = blockIdx.x*256 + threadIdx.x;     // 12288
  int l = idx / 768, c = idx - l*768;
  const float* qr = query + l*768;
  const float* wr = wq + (size_t)c*768;
  float s = 0.f;
  for(int j=0;j<768;j+=4){
    float4v a  = *(const float4v*)(qr+j);
    float4v w4 = *(const float4v*)(wr+j);
    s += a[0]*w4[0]+a[1]*w4[1]+a[2]*w4[2]+a[3]*w4[3];
  }
  q0[idx] = s;
}

// ---------------------------------------------------------------------------
// k = x @ Wk^T : proven round-4/5 structure (LDS A w/ on-stage convert,
// B register-direct, XCD swizzle) + head-major packed epilogue.
// ---------------------------------------------------------------------------
__global__ __launch_bounds__(256, 4)
void gemm_k_kernel(const float* __restrict__ x, const unsigned short* __restrict__ wh,
                   const unsigned short* __restrict__ wl, unsigned int* __restrict__ khead){
  __shared__ unsigned short Ah[128*40], Al[128*40];   // stride 40 shorts
  const int tid  = threadIdx.x;
  const int id   = blockIdx.x;          // 0..3071
  const int xcd  = id & 7, slot = id >> 3;
  const int bml  = slot / 6;            // 0..63
  const int bn   = slot - bml*6;        // 0..5
  const int bm   = xcd*64 + bml;        // 0..511
  const int wave = tid >> 6, lane = tid & 63, quad = lane >> 4, l16 = lane & 15;

  float4v acc[8][2];
  #pragma unroll
  for(int i=0;i<8;i++)
    #pragma unroll
    for(int j=0;j<2;j++) acc[i][j] = (float4v){0.f,0.f,0.f,0.f};

  const float* xA = x + (size_t)bm*128*768;
  const unsigned short* wbh = wh + (size_t)(bn*128 + wave*32 + l16)*768 + quad*8;
  const unsigned short* wbl = wl + (size_t)(bn*128 + wave*32 + l16)*768 + quad*8;

  for(int k0=0;k0<768;k0+=32){
    bf16x8 b_h[2], b_l[2];
    #pragma unroll
    for(int j=0;j<2;j++){
      b_h[j] = *(const bf16x8*)(wbh + (size_t)j*16*768 + k0);
      b_l[j] = *(const bf16x8*)(wbl + (size_t)j*16*768 + k0);
    }
    __syncthreads();
    #pragma unroll
    for(int i=0;i<2;i++){
      int fi = tid + i*256;          // 0..511
      int row = fi >> 2, c8 = fi & 3;
      const float* sp = xA + (size_t)row*768 + k0 + c8*8;
      float4v va = *(const float4v*)sp;
      float4v vb = *(const float4v*)(sp + 4);
      short8v hv, lv;
      #pragma unroll
      for(int e=0;e<4;e++){
        unsigned short hh = f2bf_hi(va[e]);
        hv[e] = (short)hh; lv[e] = (short)f2bf_hi(va[e] - bf2f(hh));
        unsigned short hh2 = f2bf_hi(vb[e]);
        hv[e+4] = (short)hh2; lv[e+4] = (short)f2bf_hi(vb[e] - bf2f(hh2));
      }
      *(short8v*)(Ah + row*40 + c8*8) = hv;
      *(short8v*)(Al + row*40 + c8*8) = lv;
    }
    __syncthreads();

    #pragma unroll
    for(int i=0;i<8;i++){
      const int ar = i*16 + l16;
      bf16x8 a_h = *(const bf16x8*)(Ah + ar*40 + quad*8);
      bf16x8 a_l = *(const bf16x8*)(Al + ar*40 + quad*8);
      #pragma unroll
      for(int j=0;j<2;j++){
        acc[i][j] = __builtin_amdgcn_mfma_f32_16x16x32_bf16(a_h, b_h[j], acc[i][j],0,0,0);
        acc[i][j] = __builtin_amdgcn_mfma_f32_16x16x32_bf16(a_l, b_h[j], acc[i][j],0,0,0);
        acc[i][j] = __builtin_amdgcn_mfma_f32_16x16x32_bf16(a_h, b_l[j], acc[i][j],0,0,0);
      }
    }
  }
  // epilogue: head-major packed store. Wave covers 32 cols within one head.
  const int b     = bm >> 5;
  const int Cbase = bn*128 + wave*32;
  const int h     = Cbase >> 6;
  const int dbase = Cbase & 63;        // 0 or 32
  const int nn0   = (bm & 31)*128;
  unsigned int* kout = khead + ((size_t)(b*12 + h)*4096 + nn0)*64 + dbase;
  #pragma unroll
  for(int i=0;i<8;i++)
    #pragma unroll
    for(int j=0;j<2;j++)
      #pragma unroll
      for(int r=0;r<4;r++)
        kout[(size_t)(i*16 + quad*4 + r)*64 + j*16 + l16] = packbf(acc[i][j][r]);
}

// ---------------------------------------------------------------------------
// attn3: one block per (b,h), 512 threads = 8 waves, 3 iterations in-kernel.
// Per round: wave stages ITS OWN 32 rows (global coalesced, swizzled LDS),
// QK (sigma-permuted A rows -> P lands in PV A-layout), exp, PV — all
// wave-local, NO barriers in the round loop. Iteration boundary: block
// reduction of acc/lsum through LDS + renorm q (softmax_1: 1 + sum).
// LDS swizzle: phi(r) = ((r&7)<<2) ^ ((r&8)<<1), stride 64 u32.
// ---------------------------------------------------------------------------
__global__ __launch_bounds__(512, 2)
void attn3_kernel(const unsigned int* __restrict__ khead,
                  const float* __restrict__ q0g, float* __restrict__ qcur){
  __shared__ unsigned int knd[256*64];            // 64 KB exactly
  float* accf  = (float*)knd;                     // [8][1024] at iter boundary
  float* lredf = (float*)knd + 8192;              // [8][16]
  float* qtmp  = (float*)knd + 8320;              // [16][64]

  const int tid  = threadIdx.x;
  const int bh   = blockIdx.x;
  const int b    = bh / 12;
  const int h    = bh - b*12;
  const int wave = tid >> 6, lane = tid & 63, quad = lane >> 4, l16 = lane & 15;

  const unsigned int* kb = khead + (size_t)(b*12 + h)*4096*64;
  // staging: thread owns tile row tid>>1, u32 half (tid&1)*32
  const int srow = tid >> 1, scol = (tid & 1)*32;
  const int sphi = ((srow & 7) << 2) ^ ((srow & 8) << 1);
  const unsigned int* kbt = kb + (size_t)srow*64 + scol;

  // QK addressing (sigma-permuted rows, wave-local)
  const int rowA = wave*32 + ((l16 >> 2) << 3) + (l16 & 3);
  const int rowB = rowA + 4;
  const int phiA = ((l16 & 3) << 2) ^ (((l16 >> 2) & 1) << 4);
  const int phiB = phiA ^ 16;
  const int q1   = quad & 1;

  // first prefetch (t=0)
  uint4v pf[8];
  #pragma unroll
  for(int g=0; g<8; ++g) pf[g] = *(const uint4v*)(kbt + g*4);

  for(int iter = 0; iter < 3; ++iter){
    // ---- q fragments (scale 1/8 folded), split hi/lo; lane l16 = l ----
    const float* qrow = (iter == 0) ? (q0g + (size_t)l16*768 + h*64)
                                    : (qtmp + l16*64);
    bf16x8 qh[2], ql[2];
    #pragma unroll
    for(int s = 0; s < 2; ++s){
      float4v v0 = *(const float4v*)(qrow + s*32 + quad*8);
      float4v v1 = *(const float4v*)(qrow + s*32 + quad*8 + 4);
      #pragma unroll
      for(int e = 0; e < 8; ++e){
        float v = (e < 4 ? v0[e] : v1[e-4]) * 0.125f;
        unsigned short hh = f2bf_hi(v);
        qh[s][e] = (short)hh;
        ql[s][e] = (short)f2bf_hi(v - bf2f(hh));
      }
    }
    __syncthreads();   // all waves done reading qtmp before LDS reuse

    float4v acc[4];
    #pragma unroll
    for(int j=0;j<4;j++) acc[j] = (float4v){0.f,0.f,0.f,0.f};
    float lsum = 0.f;

    for(int t = 0; t < 16; ++t){
      // ---- stage own 32 rows (swizzled) ----
      #pragma unroll
      for(int g=0; g<8; ++g)
        *(uint4v*)(knd + srow*64 + ((scol + g*4) ^ sphi)) = pf[g];
      // ---- prefetch next round (wraps to t=0 for next iteration) ----
      if(!(iter == 2 && t == 15)){
        const int tn = (t + 1) & 15;
        #pragma unroll
        for(int g=0; g<8; ++g) pf[g] = *(const uint4v*)(kbt + (size_t)tn*16384 + g*4);
      }

      // ---- QK: s1 rows rA-group, s2 rows rB-group ----
      float4v s1 = (float4v){0.f,0.f,0.f,0.f};
      float4v s2 = (float4v){0.f,0.f,0.f,0.f};
      #pragma unroll
      for(int s = 0; s < 2; ++s){
        const int c0 = s*32 + quad*8;
        uint4v w0 = *(const uint4v*)(knd + rowA*64 + ((c0    ) ^ phiA));
        uint4v w1 = *(const uint4v*)(knd + rowA*64 + ((c0 + 4) ^ phiA));
        uint4v u0 = *(const uint4v*)(knd + rowB*64 + ((c0    ) ^ phiB));
        uint4v u1 = *(const uint4v*)(knd + rowB*64 + ((c0 + 4) ^ phiB));
        bf16x8 a1h, a1l, a2h, a2l;
        #pragma unroll
        for(int j = 0; j < 4; ++j){
          a1h[j]   = (short)(w0[j] & 0xffffu);  a1l[j]   = (short)(w0[j] >> 16);
          a1h[j+4] = (short)(w1[j] & 0xffffu);  a1l[j+4] = (short)(w1[j] >> 16);
          a2h[j]   = (short)(u0[j] & 0xffffu);  a2l[j]   = (short)(u0[j] >> 16);
          a2h[j+4] = (short)(u1[j] & 0xffffu);  a2l[j+4] = (short)(u1[j] >> 16);
        }
        s1 = __builtin_amdgcn_mfma_f32_16x16x32_bf16(a1h, qh[s], s1, 0,0,0);
        s1 = __builtin_amdgcn_mfma_f32_16x16x32_bf16(a1l, qh[s], s1, 0,0,0);
        s1 = __builtin_amdgcn_mfma_f32_16x16x32_bf16(a1h, ql[s], s1, 0,0,0);
        s2 = __builtin_amdgcn_mfma_f32_16x16x32_bf16(a2h, qh[s], s2, 0,0,0);
        s2 = __builtin_amdgcn_mfma_f32_16x16x32_bf16(a2l, qh[s], s2, 0,0,0);
        s2 = __builtin_amdgcn_mfma_f32_16x16x32_bf16(a2h, ql[s], s2, 0,0,0);
      }

      // ---- exp + split P in registers (D-layout == PV A-layout) ----
      bf16x8 pa_h, pa_l;
      #pragma unroll
      for(int e = 0; e < 4; ++e){
        float v = __expf(s1[e]);
        lsum += v;
        unsigned short hh = f2bf_hi(v);
        pa_h[e] = (short)hh;
        pa_l[e] = (short)f2bf_hi(v - bf2f(hh));
        float v2 = __expf(s2[e]);
        lsum += v2;
        unsigned short hh2 = f2bf_hi(v2);
        pa_h[e+4] = (short)hh2;
        pa_l[e+4] = (short)f2bf_hi(v2 - bf2f(hh2));
      }

      // ---- PV over wave's 32 rows (K=32), wave-local reads ----
      const int rb0 = wave*32 + quad*8;
      #pragma unroll
      for(int j = 0; j < 4; ++j){
        bf16x8 kbh, kbl;
        #pragma unroll
        for(int e = 0; e < 8; ++e){
          const int jx = ((e >> 2) ^ q1) & 1;
          unsigned int w = knd[(rb0 + e)*64 + ((j ^ jx) << 4) + (l16 ^ ((e & 3) << 2))];
          kbh[e] = (short)(w & 0xffffu);
          kbl[e] = (short)(w >> 16);
        }
        acc[j] = __builtin_amdgcn_mfma_f32_16x16x32_bf16(pa_h, kbh, acc[j], 0,0,0);
        acc[j] = __builtin_amdgcn_mfma_f32_16x16x32_bf16(pa_l, kbh, acc[j], 0,0,0);
        acc[j] = __builtin_amdgcn_mfma_f32_16x16x32_bf16(pa_h, kbl, acc[j], 0,0,0);
      }
    } // rounds

    // ---- iteration boundary: block reduction + renorm ----
    __syncthreads();   // all waves done with knd tiles
    lsum += __shfl_xor(lsum, 16);
    lsum += __shfl_xor(lsum, 32);
    if(quad == 0) lredf[wave*16 + l16] = lsum;
    #pragma unroll
    for(int j = 0; j < 4; ++j)
      #pragma unroll
      for(int r = 0; r < 4; ++r)
        accf[wave*1024 + (quad*4 + r)*64 + j*16 + l16] = acc[j][r];
    __syncthreads();
    #pragma unroll
    for(int k = 0; k < 2; ++k){
      const int i = tid + k*512;          // 0..1023 : l=i>>6, d=i&63
      const int l = i >> 6, d = i & 63;
      float s = 0.f, lt = 1.f;
      #pragma unroll
      for(int w = 0; w < 8; ++w){ s += accf[w*1024 + i]; }
      #pragma unroll
      for(int w = 0; w < 8; ++w){ lt += lredf[w*16 + l]; }
      const float qv = s / lt;
      if(iter < 2) qtmp[i] = qv;
      else qcur[(size_t)(b*16 + l)*768 + h*64 + d] = qv;
    }
    __syncthreads();   // qtmp visible to all waves before next frag build
  } // iterations
}

// ---------------------------------------------------------------------------
// out[r][c] = sum_j inp[r][j]*W[c][j] (+bias). 4 rows x 256 cols per block.
// ---------------------------------------------------------------------------
__global__ __launch_bounds__(256)
void proj_kernel(const float* __restrict__ inp, const float* __restrict__ w,
                 const float* __restrict__ bias, float* __restrict__ out){
  __shared__ float rows[4*768];
  const int r0 = blockIdx.x*4;
  const int c  = blockIdx.y*256 + threadIdx.x;
  for(int j = threadIdx.x; j < 4*768; j += 256) rows[j] = inp[(size_t)r0*768 + j];
  __syncthreads();
  const float* wr = w + (size_t)c*768;
  float a0=0.f, a1=0.f, a2=0.f, a3=0.f;
  for(int j=0;j<768;j+=4){
    float4v w4 = *(const float4v*)(wr+j);
    float4v r0v = *(const float4v*)(rows+j);
    float4v r1v = *(const float4v*)(rows+768+j);
    float4v r2v = *(const float4v*)(rows+1536+j);
    float4v r3v = *(const float4v*)(rows+2304+j);
    #pragma unroll
    for(int e=0;e<4;e++){
      a0 += r0v[e]*w4[e]; a1 += r1v[e]*w4[e];
      a2 += r2v[e]*w4[e]; a3 += r3v[e]*w4[e];
    }
  }
  const float bb = bias ? bias[c] : 0.f;
  out[(size_t)(r0+0)*768 + c] = a0 + bb;
  out[(size_t)(r0+1)*768 + c] = a1 + bb;
  out[(size_t)(r0+2)*768 + c] = a2 + bb;
  out[(size_t)(r0+3)*768 + c] = a3 + bb;
}

// ---------------------------------------------------------------------------
extern "C" void kernel_launch(void* const* d_in, const int* in_sizes, int n_in,
                              void* d_out, int out_size, void* d_ws, size_t ws_size,
                              hipStream_t stream){
  const float* x     = (const float*)d_in[0];   // [16,4096,768]
  const float* query = (const float*)d_in[1];   // [1,16,768]
  const float* Wq    = (const float*)d_in[2];   // [768,768]
  const float* Wk    = (const float*)d_in[3];
  const float* Wv    = (const float*)d_in[4];
  const float* Wproj = (const float*)d_in[5];
  const float* bproj = (const float*)d_in[6];   // [768]
  float* out = (float*)d_out;                   // [16,16,768] fp32

  char* ws = (char*)d_ws;
  unsigned int*   khead = (unsigned int*)(ws);           // 201326592 B
  float*          qcur  = (float*)(ws + 201326592);      // 786432 B
  float*          q0    = (float*)(ws + 202113024);      // 49152 B
  char*           R     = ws + 202162176;                // 2359296 B region
  unsigned short* wkh   = (unsigned short*)(R);          // gemm phase
  unsigned short* wkl   = (unsigned short*)(R + 1179648);
  float*          out1  = (float*)(R);                   // proj phase (alias)

  cvt_planar_kernel<<<576, 256, 0, stream>>>(Wk, wkh, wkl);
  q0_kernel<<<48, 256, 0, stream>>>(query, Wq, q0);
  gemm_k_kernel<<<3072, 256, 0, stream>>>(x, wkh, wkl, khead);

  attn3_kernel<<<192, 512, 0, stream>>>(khead, q0, qcur);

  proj_kernel<<<dim3(64, 3), 256, 0, stream>>>(qcur, Wv, nullptr, out1);
  proj_kernel<<<dim3(64, 3), 256, 0, stream>>>(out1, Wproj, bproj, out);
}